// Round 5
// baseline (2873.469 us; speedup 1.0000x reference)
//
#include <hip/hip_runtime.h>
#include <math.h>

#define T_ 16
#define B_ 128
#define C3 24
#define OUT_ 64
#define NT 768
#define EPS_ 1e-5f
#define TPs 776      // s_tP row stride (dwords)
#define CBS 3456     // chunk buffer size (dwords): 12 kb * 288
#define KBR 288      // per-kb stride in chunk buffer
#define CS 36        // per-col stride in chunk buffer

typedef __attribute__((ext_vector_type(8))) short bf16x8;
typedef __attribute__((ext_vector_type(4))) float f32x4;

union FragU { unsigned u[4]; bf16x8 f; };

__device__ __forceinline__ unsigned packsplit(float x) {
    unsigned u = __float_as_uint(x);
    unsigned h = (u + 0x7fffu + ((u >> 16) & 1u)) & 0xffff0000u;
    float r = x - __uint_as_float(h);
    unsigned v = __float_as_uint(r);
    unsigned l = (v + 0x7fffu + ((v >> 16) & 1u)) >> 16;
    return h | l;
}
__device__ __forceinline__ float unpack2f(unsigned p) {
    return __uint_as_float(p & 0xffff0000u) + __uint_as_float(p << 16);
}
__device__ __forceinline__ void unpack_frags(const unsigned* p, bf16x8& hi, bf16x8& lo) {
    FragU H, L;
#pragma unroll
    for (int q = 0; q < 4; ++q) {
        H.u[q] = (p[2*q] >> 16) | (p[2*q+1] & 0xffff0000u);
        L.u[q] = (p[2*q] & 0xffffu) | (p[2*q+1] << 16);
    }
    hi = H.f; lo = L.f;
}
__device__ __forceinline__ f32x4 mfma16(bf16x8 a, bf16x8 b, f32x4 c) {
    return __builtin_amdgcn_mfma_f32_16x16x32_bf16(a, b, c, 0, 0, 0);
}

// ---------- prep: Wr -> fragment-major hi/lo planes ----------
__global__ void prep_wrf(const float* __restrict__ Wr, short* __restrict__ Fhi, short* __restrict__ Flo) {
    int idx = blockIdx.x * 256 + threadIdx.x;
    if (idx >= 884736) return;
    int j = idx & 7, lane = (idx >> 3) & 63, kb = (idx >> 9) % 288, rt = idx / (512 * 288);
    int col = lane & 15, grp = lane >> 4;
    int r = rt * 16 + col, k = kb * 32 + grp * 8 + j;
    float x = Wr[(size_t)k * 96 + r];
    unsigned u = __float_as_uint(x);
    unsigned h = (u + 0x7fffu + ((u >> 16) & 1u)) & 0xffff0000u;
    float res = x - __uint_as_float(h);
    unsigned v = __float_as_uint(res);
    Fhi[idx] = (short)(h >> 16);
    Flo[idx] = (short)((v + 0x7fffu + ((v >> 16) & 1u)) >> 16);
}
__global__ void prep_w2f(const float* __restrict__ W2, short* __restrict__ Fhi, short* __restrict__ Flo) {
    int idx = blockIdx.x * 256 + threadIdx.x;
    if (idx >= 73728) return;
    int j = idx & 7, lane = (idx >> 3) & 63, kb = (idx >> 9) % 24, rt = idx / (512 * 24);
    int col = lane & 15, grp = lane >> 4;
    int f = rt * 16 + col, k = kb * 32 + grp * 8 + j;
    float x = W2[(size_t)k * 96 + f];
    unsigned u = __float_as_uint(x);
    unsigned h = (u + 0x7fffu + ((u >> 16) & 1u)) & 0xffff0000u;
    float res = x - __uint_as_float(h);
    unsigned v = __float_as_uint(res);
    Fhi[idx] = (short)(h >> 16);
    Flo[idx] = (short)((v + 0x7fffu + ((v >> 16) & 1u)) >> 16);
}
__global__ __launch_bounds__(NT, 1) void y0_kernel(const float* __restrict__ rel_bias,
                                                   const float* __restrict__ Wr,
                                                   float* __restrict__ y0) {
    __shared__ float s[NT];
    const int n = blockIdx.x;
    const int tid = threadIdx.x;
    const int r = tid % 96, p = tid / 96;
    const float* rb = rel_bias + n * 9216;
    float acc = 0.f;
    for (int i = p * 1152; i < (p + 1) * 1152; ++i)
        acc += rb[i] * Wr[(size_t)i * 96 + r];
    s[tid] = acc;
    __syncthreads();
    if (tid < 96) {
        float tot = 0.f;
        for (int q = 0; q < 8; ++q) tot += s[q * 96 + tid];
        y0[n * 96 + tid] = tot;
    }
}

// ---------------- main scan: 2 blocks per batch (rt-split heavy) ----------------
__global__ __launch_bounds__(NT, 3) void stm_kernel(
    const float* __restrict__ x, const float* __restrict__ Wqkv, const float* __restrict__ bqkv,
    const float* __restrict__ ln_g, const float* __restrict__ ln_b,
    const float* __restrict__ a1p, const float* __restrict__ a2p, const float* __restrict__ a3p,
    const float* __restrict__ b2, const float* __restrict__ br,
    const float* __restrict__ W3, const float* __restrict__ b3,
    const float* __restrict__ item_bias, const float* __restrict__ rel_bias,
    const float* __restrict__ y0g,
    const short* __restrict__ WrH, const short* __restrict__ WrL,
    const short* __restrict__ W2H, const short* __restrict__ W2L,
    float* __restrict__ out)
{
    __shared__ float s_Q[2304];
    __shared__ __attribute__((aligned(16))) unsigned s_scr[6912];
    __shared__ __attribute__((aligned(16))) unsigned s_tP[8 * TPs];
    __shared__ float s_tsum[768];
    __shared__ float s_v[768];
    __shared__ float s_G[768];
    __shared__ float s_y[384];           // [n][48] this block's half
    __shared__ float s_xt[96];
    __shared__ float s_xtWq[24];
    __shared__ float s_GWq[192];
    __shared__ float s_b2Wq[24];
    __shared__ float s_Vtr[96];
    __shared__ float s_br[96];
    __shared__ float s_red[32];
    __shared__ float s_mu, s_rstd;
    __shared__ float s_pad[2200];        // push LDS > 80 KB: force 1 block/CU -> 256 CUs

    const int tid = threadIdx.x;
    const int b = blockIdx.x >> 1;
    const int h = blockIdx.x & 1;        // heavy half: rt in [3h, 3h+3)
    const int wv = tid >> 6, lane = tid & 63, col = lane & 15, grp = lane >> 4;
    const float a1 = a1p[0], a2 = a2p[0], a3 = a3p[0];
    float* scr = (float*)s_scr;

    // register-resident Mi/S: thread owns (de, ef0..ef0+12)
    const int de = tid >> 3, ef0 = (tid & 7) * 12;
    float rMi[12], rS[12], rb2[12];
#pragma unroll
    for (int ii = 0; ii < 12; ++ii) {
        rMi[ii] = item_bias[de * 96 + ef0 + ii];
        float ss = 0.f;
        for (int n = 0; n < 8; ++n) ss += rel_bias[n * 9216 + de * 96 + ef0 + ii];
        rS[ii] = ss;
        rb2[ii] = b2[ef0 + ii];
    }
    // build-phase mapping
    const int bn = tid & 7;
    const int bg = tid >> 3;
    const int bk0 = bg * 4;
    const int bdl = bk0 / 96;
    const int be0 = bk0 % 96;
    const int bkb = bk0 >> 5;
    const int bj0 = bk0 & 31;

    // ---- init ----
    if (tid < 384) s_y[tid] = y0g[(tid / 48) * 96 + h * 48 + (tid % 48)];
    if (tid < 96) s_br[tid] = br[tid];
    if (tid >= 96 && tid < 96 + 2200 && tid - 96 < 2200) s_pad[tid - 96] = 0.f; // keep pad live
    for (int pp = 0; pp < 3; ++pp) {
        int o = tid + NT * pp; int i = o / C3, c = o % C3;
        float acc = 0.f;
        const float* ib = item_bias + i * 96;
        for (int k = 0; k < 96; ++k) acc += ib[k] * Wqkv[k * C3 + c];
        s_Q[o] = acc;
    }
    { int c = tid % C3, p = tid / C3; float acc = 0.f;
      for (int k = 3 * p; k < 3 * p + 3; ++k) acc += b2[k] * Wqkv[k * C3 + c];
      scr[tid] = acc; }
    __syncthreads();
    if (tid < C3) { float a = 0.f; for (int p = 0; p < 32; ++p) a += scr[p * C3 + tid]; s_b2Wq[tid] = a; }
    __syncthreads();

    for (int t = 0; t < T_; ++t) {
        // 1: xt
        if (tid < 96) s_xt[tid] = x[((size_t)t * B_ + b) * 96 + tid];
        __syncthreads();
        // 2: Mi += xt xt^T (registers) ; xtWq partials
        {
            float xde = s_xt[de];
            const float4* xp = (const float4*)&s_xt[ef0];
            float4 x0 = xp[0], x1 = xp[1], x2 = xp[2];
            rMi[0] += xde * x0.x; rMi[1] += xde * x0.y; rMi[2] += xde * x0.z; rMi[3] += xde * x0.w;
            rMi[4] += xde * x1.x; rMi[5] += xde * x1.y; rMi[6] += xde * x1.z; rMi[7] += xde * x1.w;
            rMi[8] += xde * x2.x; rMi[9] += xde * x2.y; rMi[10] += xde * x2.z; rMi[11] += xde * x2.w;
        }
        { int c = tid % C3, p = tid / C3; float acc = 0.f;
          for (int k = 3 * p; k < 3 * p + 3; ++k) acc += s_xt[k] * Wqkv[k * C3 + c];
          scr[tid] = acc; }
        __syncthreads();
        // 3: xtWq final ; Vtr partials (register products + in-wave reduce over de-octets)
        if (tid < C3) { float a = 0.f; for (int p = 0; p < 32; ++p) a += scr[p * C3 + tid]; s_xtWq[tid] = a; }
        {
            float p12[12];
#pragma unroll
            for (int ii = 0; ii < 12; ++ii) p12[ii] = rMi[ii] * rS[ii];
#pragma unroll
            for (int ii = 0; ii < 12; ++ii) {
                p12[ii] += __shfl_xor(p12[ii], 8);
                p12[ii] += __shfl_xor(p12[ii], 16);
                p12[ii] += __shfl_xor(p12[ii], 32);
            }
            if ((lane >> 3) == 0) {
#pragma unroll
                for (int ii = 0; ii < 12; ++ii)
                    scr[1536 + wv * 96 + (lane & 7) * 12 + ii] = p12[ii];
            }
        }
        __syncthreads();
        // 4: Vtr final ; Q += xt ⊗ xtWq
        if (tid < 96) { float a = 0.f; for (int w = 0; w < 12; ++w) a += scr[1536 + w * 96 + tid]; s_Vtr[tid] = a; }
        for (int pp = 0; pp < 3; ++pp) { int o = tid + NT * pp; int i = o / C3, c = o % C3;
            s_Q[o] += s_xt[i] * s_xtWq[c]; }
        __syncthreads();
        // 5: qkv_pre -> scr[0..2304) + LN sums
        {
            float ls = 0.f, lq = 0.f;
            for (int pp = 0; pp < 3; ++pp) {
                int o = tid + NT * pp; int i = o / C3, c = o % C3;
                float q = s_Q[o] + a2 * s_Vtr[i] * s_xtWq[c] + bqkv[c];
                scr[o] = q; ls += q; lq += q * q;
            }
            for (int off = 32; off > 0; off >>= 1) { ls += __shfl_down(ls, off); lq += __shfl_down(lq, off); }
            if (lane == 0) { s_red[wv] = ls; s_red[16 + wv] = lq; }
        }
        __syncthreads();
        if (tid == 0) {
            float S = 0.f, Qs = 0.f;
            for (int w = 0; w < 12; ++w) { S += s_red[w]; Qs += s_red[16 + w]; }
            float mu = S * (1.0f / 2304.f);
            float var = Qs * (1.0f / 2304.f) - mu * mu;
            s_mu = mu; s_rstd = rsqrtf(var + EPS_);
        }
        __syncthreads();
        // 7: LN apply
        { float mu = s_mu, rs = s_rstd;
          for (int pp = 0; pp < 3; ++pp) { int o = tid + NT * pp;
              scr[o] = (scr[o] - mu) * rs * ln_g[o] + ln_b[o]; } }
        __syncthreads();
        // 8: v copy + t (fp32 tanh, exact fp32 tsum, packed-split store)
        { int j = tid / 96, e = tid % 96; s_v[tid] = scr[e * C3 + 16 + j]; }
        {
            int j = tid / 96, d = tid % 96;
            float kk = scr[d * C3 + 8 + j];
            float ts = 0.f;
#pragma unroll
            for (int n = 0; n < 8; ++n) {
                float tv = tanhf(scr[d * C3 + n] * kk);
                ts += tv;
                s_tP[j * TPs + n * 96 + d] = packsplit(tv);
            }
            s_tsum[j * 96 + d] = ts;
        }
        __syncthreads();
        // 9: G-GEMM (full, duplicated per block)
        {
            const int rt = wv % 6, kh = wv / 6;
            f32x4 accG = {0.f, 0.f, 0.f, 0.f};
#pragma unroll
            for (int s2 = 0; s2 < 12; ++s2) {
                int kb = kh * 12 + s2;
                unsigned pa[8] = {0,0,0,0,0,0,0,0};
                if (col < 8) {
                    const uint4* q0 = (const uint4*)&s_tP[col * TPs + kb * 32 + grp * 8];
                    uint4 x0 = q0[0], x1 = q0[1];
                    pa[0]=x0.x; pa[1]=x0.y; pa[2]=x0.z; pa[3]=x0.w;
                    pa[4]=x1.x; pa[5]=x1.y; pa[6]=x1.z; pa[7]=x1.w;
                }
                bf16x8 ah, al; unpack_frags(pa, ah, al);
                int fo = ((rt * 24 + kb) * 64 + lane) * 8;
                bf16x8 bh = *(const bf16x8*)&W2H[fo];
                bf16x8 bl = *(const bf16x8*)&W2L[fo];
                accG = mfma16(ah, bh, accG);
                accG = mfma16(al, bh, accG);
                accG = mfma16(ah, bl, accG);
                accG = mfma16(al, bl, accG);
            }
            if (kh == 0 && grp < 2) {
#pragma unroll
                for (int reg = 0; reg < 4; ++reg)
                    s_G[(grp * 4 + reg) * 96 + rt * 16 + col] = accG[reg];
            }
            __syncthreads();
            if (kh == 1 && grp < 2) {
#pragma unroll
                for (int reg = 0; reg < 4; ++reg)
                    s_G[(grp * 4 + reg) * 96 + rt * 16 + col] += accG[reg];
            }
        }
        __syncthreads();
        // 10: GWq partials + S/Mi register updates
        { int oo = tid % 192, p = tid / 192; int jg = oo / C3, cc = oo % C3;
          float a = 0.f;
          for (int f = p * 24; f < p * 24 + 24; ++f) a += s_G[jg * 96 + f] * Wqkv[f * C3 + cc];
          scr[tid] = a; }
        {
            float tj[8], vj[8];
#pragma unroll
            for (int j = 0; j < 8; ++j) { tj[j] = s_tsum[j * 96 + de]; vj[j] = s_v[j * 96 + de]; }
            float sn[12], r2[12];
#pragma unroll
            for (int ii = 0; ii < 12; ++ii) { sn[ii] = 0.f; r2[ii] = rb2[ii]; }
#pragma unroll
            for (int j = 0; j < 8; ++j) {
                const float4* vp = (const float4*)&s_v[j * 96 + ef0];
                const float4* gp = (const float4*)&s_G[j * 96 + ef0];
#pragma unroll
                for (int q4 = 0; q4 < 3; ++q4) {
                    float4 vv = vp[q4], gg = gp[q4];
                    sn[q4 * 4 + 0] += tj[j] * vv.x; sn[q4 * 4 + 1] += tj[j] * vv.y;
                    sn[q4 * 4 + 2] += tj[j] * vv.z; sn[q4 * 4 + 3] += tj[j] * vv.w;
                    r2[q4 * 4 + 0] += vj[j] * gg.x; r2[q4 * 4 + 1] += vj[j] * gg.y;
                    r2[q4 * 4 + 2] += vj[j] * gg.z; r2[q4 * 4 + 3] += vj[j] * gg.w;
                }
            }
#pragma unroll
            for (int ii = 0; ii < 12; ++ii) {
                rS[ii] = a1 * rS[ii] + sn[ii];
                rMi[ii] += a3 * r2[ii];
            }
        }
        __syncthreads();
        // 11: GWq final
        if (tid < 192) s_GWq[tid] = scr[tid] + scr[192 + tid] + scr[384 + tid] + scr[576 + tid];
        __syncthreads();
        // 12: Q += a3*(v^T GWq + b2Wq)
        for (int pp = 0; pp < 3; ++pp) {
            int o = tid + NT * pp; int i = o / C3, c = o % C3;
            float a = s_b2Wq[c];
#pragma unroll
            for (int j = 0; j < 8; ++j) a += s_v[j * 96 + i] * s_GWq[j * C3 + c];
            s_Q[o] += a3 * a;
        }
        // ---- heavy: this block's half (rt 3h..3h+2), 24 chunks x 4 d, double-buffered ----
        f32x4 acc[3];
#pragma unroll
        for (int rt = 0; rt < 3; ++rt) acc[rt] = (f32x4){0.f, 0.f, 0.f, 0.f};
        {
            float r0 = 0.f, r1 = 0.f, r2v = 0.f, r3 = 0.f;
            int d = bdl;
#pragma unroll
            for (int j = 0; j < 8; ++j) {
                float tj = unpack2f(s_tP[j * TPs + bn * 96 + d]);
                float4 v4 = *(const float4*)&s_v[j * 96 + be0];
                r0 += tj * v4.x; r1 += tj * v4.y; r2v += tj * v4.z; r3 += tj * v4.w;
            }
            uint4 w; w.x = packsplit(r0); w.y = packsplit(r1); w.z = packsplit(r2v); w.w = packsplit(r3);
            *(uint4*)&s_scr[bkb * KBR + bn * CS + bj0] = w;
        }
        for (int ch = 0; ch < 24; ++ch) {
            __syncthreads();
            {
                const unsigned* buf = s_scr + (ch & 1) * CBS;
                unsigned pa[8] = {0,0,0,0,0,0,0,0};
                if (col < 8) {
                    const uint4* q0 = (const uint4*)&buf[wv * KBR + col * CS + grp * 8];
                    uint4 x0 = q0[0], x1 = q0[1];
                    pa[0]=x0.x; pa[1]=x0.y; pa[2]=x0.z; pa[3]=x0.w;
                    pa[4]=x1.x; pa[5]=x1.y; pa[6]=x1.z; pa[7]=x1.w;
                }
                bf16x8 ah, al; unpack_frags(pa, ah, al);
                const int kbg = ch * 12 + wv;
                const int fbase = (kbg * 64 + lane) * 8;
#pragma unroll
                for (int rt = 0; rt < 3; ++rt) {
                    int fo = (h * 3 + rt) * 147456 + fbase;
                    bf16x8 bh = *(const bf16x8*)&WrH[fo];
                    bf16x8 bl = *(const bf16x8*)&WrL[fo];
                    acc[rt] = mfma16(ah, bh, acc[rt]);
                    acc[rt] = mfma16(al, bh, acc[rt]);
                    acc[rt] = mfma16(ah, bl, acc[rt]);
                }
            }
            if (ch < 23) {
                float r0 = 0.f, r1 = 0.f, r2v = 0.f, r3 = 0.f;
                int d = (ch + 1) * 4 + bdl;
#pragma unroll
                for (int j = 0; j < 8; ++j) {
                    float tj = unpack2f(s_tP[j * TPs + bn * 96 + d]);
                    float4 v4 = *(const float4*)&s_v[j * 96 + be0];
                    r0 += tj * v4.x; r1 += tj * v4.y; r2v += tj * v4.z; r3 += tj * v4.w;
                }
                uint4 w; w.x = packsplit(r0); w.y = packsplit(r1); w.z = packsplit(r2v); w.w = packsplit(r3);
                *(uint4*)&s_scr[((ch + 1) & 1) * CBS + bkb * KBR + bn * CS + bj0] = w;
            }
        }
        __syncthreads();
        // reduce 12 wave-partials into y (this half: 48 cols)
        if (wv < 6 && grp < 2) {
#pragma unroll
            for (int rt = 0; rt < 3; ++rt)
#pragma unroll
                for (int reg = 0; reg < 4; ++reg)
                    scr[(wv * 8 + grp * 4 + reg) * 48 + rt * 16 + col] = acc[rt][reg];
        }
        __syncthreads();
        if (wv >= 6 && grp < 2) {
#pragma unroll
            for (int rt = 0; rt < 3; ++rt)
#pragma unroll
                for (int reg = 0; reg < 4; ++reg)
                    scr[((wv - 6) * 8 + grp * 4 + reg) * 48 + rt * 16 + col] += acc[rt][reg];
        }
        __syncthreads();
        if (tid < 384) {
            int n = tid / 48, rl = tid % 48;
            float a = 0.f;
            for (int w = 0; w < 6; ++w) a += scr[(w * 8 + n) * 48 + rl];
            s_y[tid] = a1 * s_y[tid] + a;
        }
        __syncthreads();
        // out partial: this block's 384 i's, atomicAdd combine
        {
            int o = tid & 63, qq = tid >> 6;
            float a = 0.f;
            for (int il = qq * 32; il < qq * 32 + 32; ++il) {
                int n = il / 48, rl = il % 48;
                a += (s_y[il] + s_br[h * 48 + rl]) * W3[(size_t)(n * 96 + h * 48 + rl) * 64 + o];
            }
            scr[tid] = a;
        }
        __syncthreads();
        if (tid < 64) {
            float a = (h == 0) ? b3[tid] : 0.f;
            for (int q = 0; q < 12; ++q) a += scr[q * 64 + tid];
            atomicAdd(&out[((size_t)t * B_ + b) * OUT_ + tid], a);
        }
        __syncthreads();
    }
    // keep s_pad from being optimized out (never true at runtime)
    if (tid == 0xFFFFF) out[0] = s_pad[0];
}

extern "C" void kernel_launch(void* const* d_in, const int* in_sizes, int n_in,
                              void* d_out, int out_size, void* d_ws, size_t ws_size,
                              hipStream_t stream) {
    const float* x         = (const float*)d_in[0];
    const float* Wqkv      = (const float*)d_in[1];
    const float* bqkv      = (const float*)d_in[2];
    const float* ln_g      = (const float*)d_in[3];
    const float* ln_b      = (const float*)d_in[4];
    const float* a1        = (const float*)d_in[5];
    const float* a2        = (const float*)d_in[6];
    const float* a3        = (const float*)d_in[7];
    const float* W2        = (const float*)d_in[8];
    const float* b2        = (const float*)d_in[9];
    const float* Wr        = (const float*)d_in[10];
    const float* br        = (const float*)d_in[11];
    const float* W3        = (const float*)d_in[12];
    const float* b3        = (const float*)d_in[13];
    const float* item_bias = (const float*)d_in[14];
    const float* rel_bias  = (const float*)d_in[15];
    float* out = (float*)d_out;

    char* ws = (char*)d_ws;
    short* WrH = (short*)ws;                               // 1,769,472 B
    short* WrL = (short*)(ws + 1769472);                   // 1,769,472 B
    short* W2H = (short*)(ws + 2 * 1769472);               //   147,456 B
    short* W2L = (short*)(ws + 2 * 1769472 + 147456);      //   147,456 B
    float* y0  = (float*)(ws + 2 * 1769472 + 2 * 147456);  //     3,072 B

    hipMemsetAsync(out, 0, (size_t)out_size * sizeof(float), stream);
    hipLaunchKernelGGL(prep_wrf, dim3(3456), dim3(256), 0, stream, Wr, WrH, WrL);
    hipLaunchKernelGGL(prep_w2f, dim3(288), dim3(256), 0, stream, W2, W2H, W2L);
    hipLaunchKernelGGL(y0_kernel, dim3(8), dim3(NT), 0, stream, rel_bias, Wr, y0);
    hipLaunchKernelGGL(stm_kernel, dim3(2 * B_), dim3(NT), 0, stream,
                       x, Wqkv, bqkv, ln_g, ln_b, a1, a2, a3,
                       b2, br, W3, b3, item_bias, rel_bias,
                       y0, WrH, WrL, W2H, W2L, out);
}